// Round 1
// 1073.593 us; speedup vs baseline: 1.0810x; 1.0810x over previous
//
#include <hip/hip_runtime.h>
#include <math.h>

#define DDIM 2048
#define NCAND 65536
#define KSPLIT 32

// ---------------------------------------------------------------------------
// Kernel A: partial sums of align_pre[j] = sum_k word[k] * W[k, j]
// float4 over j: 1 KB per wave load instruction (was 256 B scalar).
// Both sides (l, r) computed in one pass over W (W read once: 16 MB).
// ---------------------------------------------------------------------------
__global__ void align_partial(const float* __restrict__ wl,
                              const float* __restrict__ wr,
                              const float* __restrict__ W,
                              float* __restrict__ alignp) {
    const int j4 = blockIdx.x * blockDim.x + threadIdx.x;   // 0..511
    const int kc = blockIdx.y;                              // 0..KSPLIT-1
    const int kchunk = DDIM / KSPLIT;
    const int k0 = kc * kchunk;
    float4 al = make_float4(0.f, 0.f, 0.f, 0.f);
    float4 ar = make_float4(0.f, 0.f, 0.f, 0.f);
    for (int k = k0; k < k0 + kchunk; ++k) {
        const float4 w = *(const float4*)(W + (size_t)k * DDIM + j4 * 4);
        const float cl = wl[k], cr = wr[k];
        al.x = fmaf(cl, w.x, al.x); al.y = fmaf(cl, w.y, al.y);
        al.z = fmaf(cl, w.z, al.z); al.w = fmaf(cl, w.w, al.w);
        ar.x = fmaf(cr, w.x, ar.x); ar.y = fmaf(cr, w.y, ar.y);
        ar.z = fmaf(cr, w.z, ar.z); ar.w = fmaf(cr, w.w, ar.w);
    }
    *(float4*)(alignp + (size_t)(0 * KSPLIT + kc) * DDIM + j4 * 4) = al;
    *(float4*)(alignp + (size_t)(1 * KSPLIT + kc) * DDIM + j4 * 4) = ar;
}

// ---------------------------------------------------------------------------
// Kernel B: align[j] = tanh(sum_kc partial + b[j]), both sides.
// ---------------------------------------------------------------------------
__global__ void align_finish(const float* __restrict__ alignp,
                             const float* __restrict__ b,
                             float* __restrict__ alignv) {
    const int j = blockIdx.x * blockDim.x + threadIdx.x;
    float sl = b[j], sr = b[j];
    for (int kc = 0; kc < KSPLIT; ++kc) {
        sl += alignp[(size_t)(0 * KSPLIT + kc) * DDIM + j];
        sr += alignp[(size_t)(1 * KSPLIT + kc) * DDIM + j];
    }
    alignv[j] = tanhf(sl);
    alignv[DDIM + j] = tanhf(sr);
}

// ---------------------------------------------------------------------------
// Kernel C: fused scores -> online softmax -> weighted accumulation.
// PER-WAVE: each wave owns rows_per_wave rows across all 2048 cols.
// Changes vs prior version:
//   1. Dot product uses 4 independent FMA chains (serial dep 128cy -> ~40cy).
//   2. Redundant lane-0 re-broadcast removed (xor-butterfly is already
//      bit-identical across lanes: fp add is commutative).
//   3. SKIP path: if p - m < -25 (wave-uniform), wgt < 1.4e-11 cannot change
//      s (>=1, ulp 6e-8) or acc in fp32 -> skip exp + 32 accumulate FMAs
//      entirely. With sigma(score) ~ 45, ~85% of rows skip.
// ---------------------------------------------------------------------------
__global__ __launch_bounds__(256, 4) void score_accum(
    const float* __restrict__ cand_l, const float* __restrict__ cand_r,
    const float* __restrict__ alignv,
    float* __restrict__ accP, float* __restrict__ mP, float* __restrict__ sP,
    int B, int rows_per_wave)
{
    const int side = blockIdx.y;
    const float* __restrict__ cand  = (side == 0) ? cand_r : cand_l;
    const float* __restrict__ align = alignv + (size_t)side * DDIM;

    const int t = threadIdx.x;
    const int w = t >> 6;
    const int l = t & 63;
    const int cbase = l * 4;

    float4 al[8], acc[8];
#pragma unroll
    for (int c = 0; c < 8; ++c) {
        al[c]  = *(const float4*)(align + c * 256 + cbase);
        acc[c] = make_float4(0.f, 0.f, 0.f, 0.f);
    }
    float m = -INFINITY, s = 0.f;

    const int row0 = (blockIdx.x * 4 + w) * rows_per_wave;
    for (int r = 0; r < rows_per_wave; ++r) {
        const float* rp = cand + (size_t)(row0 + r) * DDIM;
        float4 v[8];
#pragma unroll
        for (int c = 0; c < 8; ++c)
            v[c] = *(const float4*)(rp + c * 256 + cbase);

        // 4 independent partial dot chains
        float pp[4] = {0.f, 0.f, 0.f, 0.f};
#pragma unroll
        for (int c = 0; c < 8; ++c) {
            float q = pp[c >> 1];
            q = fmaf(v[c].x, al[c].x, q);
            q = fmaf(v[c].y, al[c].y, q);
            q = fmaf(v[c].z, al[c].z, q);
            q = fmaf(v[c].w, al[c].w, q);
            pp[c >> 1] = q;
        }
        float p = (pp[0] + pp[1]) + (pp[2] + pp[3]);
#pragma unroll
        for (int off = 32; off > 0; off >>= 1)
            p += __shfl_xor(p, off, 64);
        // all lanes now hold bit-identical p (xor-butterfly + commutative add)

        if (p > m) {                   // wave-uniform, ~ln(rows) times
            const float alpha = expf(m - p); // m=-inf first hit -> alpha=0
            m = p;
            s = fmaf(s, alpha, 1.f);   // new-max weight = 1
#pragma unroll
            for (int c = 0; c < 8; ++c) {
                acc[c].x = fmaf(acc[c].x, alpha, v[c].x);
                acc[c].y = fmaf(acc[c].y, alpha, v[c].y);
                acc[c].z = fmaf(acc[c].z, alpha, v[c].z);
                acc[c].w = fmaf(acc[c].w, alpha, v[c].w);
            }
        } else if (p - m >= -25.f) {   // contributes at fp32 resolution
            const float wgt = expf(p - m);
            s += wgt;
#pragma unroll
            for (int c = 0; c < 8; ++c) {
                acc[c].x = fmaf(wgt, v[c].x, acc[c].x);
                acc[c].y = fmaf(wgt, v[c].y, acc[c].y);
                acc[c].z = fmaf(wgt, v[c].z, acc[c].z);
                acc[c].w = fmaf(wgt, v[c].w, acc[c].w);
            }
        }
        // else: wgt < 1.4e-11 -> cannot alter s or acc in fp32; skip.
    }

    // ---- merge 4 wave-partials -> 1 block-partial via LDS (single barrier)
    __shared__ float sh_acc[4][DDIM];
    __shared__ float sh_m[4], sh_s[4];
#pragma unroll
    for (int c = 0; c < 8; ++c)
        *(float4*)(&sh_acc[w][c * 256 + cbase]) = acc[c];
    if (l == 0) { sh_m[w] = m; sh_s[w] = s; }
    __syncthreads();

    const float mB = fmaxf(fmaxf(sh_m[0], sh_m[1]), fmaxf(sh_m[2], sh_m[3]));
    const float e0 = expf(sh_m[0] - mB);
    const float e1 = expf(sh_m[1] - mB);
    const float e2 = expf(sh_m[2] - mB);
    const float e3 = expf(sh_m[3] - mB);
    const float sB = e0 * sh_s[0] + e1 * sh_s[1] + e2 * sh_s[2] + e3 * sh_s[3];

    float* accB = accP + (size_t)(side * B + blockIdx.x) * DDIM;
#pragma unroll
    for (int half = 0; half < 2; ++half) {
        const int col = half * 1024 + t * 4;
        const float4 a0 = *(const float4*)&sh_acc[0][col];
        const float4 a1 = *(const float4*)&sh_acc[1][col];
        const float4 a2 = *(const float4*)&sh_acc[2][col];
        const float4 a3 = *(const float4*)&sh_acc[3][col];
        float4 o;
        o.x = e0 * a0.x + e1 * a1.x + e2 * a2.x + e3 * a3.x;
        o.y = e0 * a0.y + e1 * a1.y + e2 * a2.y + e3 * a3.y;
        o.z = e0 * a0.z + e1 * a1.z + e2 * a2.z + e3 * a3.z;
        o.w = e0 * a0.w + e1 * a1.w + e2 * a2.w + e3 * a3.w;
        *(float4*)(accB + col) = o;
    }
    if (t == 0) {
        mP[side * B + blockIdx.x] = mB;
        sP[side * B + blockIdx.x] = sB;
    }
}

// ---------------------------------------------------------------------------
// Kernel D: combine block partials:
// out[j] = sum_b e^{m_b-M} acc_b[j] / sum_b e^{m_b-M} s_b
// Unrolled x4 with independent partials to break the 512-deep serial chains.
// ---------------------------------------------------------------------------
__global__ void combine(const float* __restrict__ accP,
                        const float* __restrict__ mP,
                        const float* __restrict__ sP,
                        float* __restrict__ out, int B)
{
    const int side = blockIdx.y;
    const int j = blockIdx.x * blockDim.x + threadIdx.x;
    const float* m = mP + side * B;
    const float* s = sP + side * B;
    float M0 = -INFINITY, M1 = -INFINITY, M2 = -INFINITY, M3 = -INFINITY;
    for (int b = 0; b < B; b += 4) {
        M0 = fmaxf(M0, m[b]);
        M1 = fmaxf(M1, m[b + 1]);
        M2 = fmaxf(M2, m[b + 2]);
        M3 = fmaxf(M3, m[b + 3]);
    }
    const float M = fmaxf(fmaxf(M0, M1), fmaxf(M2, M3));

    float S0 = 0.f, S1 = 0.f, S2 = 0.f, S3 = 0.f;
    float n0 = 0.f, n1 = 0.f, n2 = 0.f, n3 = 0.f;
    const float* ap = accP + (size_t)side * B * DDIM + j;
    for (int b = 0; b < B; b += 4) {
        const float w0 = expf(m[b]     - M);
        const float w1 = expf(m[b + 1] - M);
        const float w2 = expf(m[b + 2] - M);
        const float w3 = expf(m[b + 3] - M);
        S0 += w0 * s[b];     S1 += w1 * s[b + 1];
        S2 += w2 * s[b + 2]; S3 += w3 * s[b + 3];
        n0 = fmaf(w0, ap[(size_t)(b)     * DDIM], n0);
        n1 = fmaf(w1, ap[(size_t)(b + 1) * DDIM], n1);
        n2 = fmaf(w2, ap[(size_t)(b + 2) * DDIM], n2);
        n3 = fmaf(w3, ap[(size_t)(b + 3) * DDIM], n3);
    }
    out[(size_t)side * DDIM + j] =
        ((n0 + n1) + (n2 + n3)) / ((S0 + S1) + (S2 + S3));
}

extern "C" void kernel_launch(void* const* d_in, const int* in_sizes, int n_in,
                              void* d_out, int out_size, void* d_ws, size_t ws_size,
                              hipStream_t stream) {
    const float* wl = (const float*)d_in[0];  // embed_word_l [1,D]
    const float* wr = (const float*)d_in[1];  // embed_word_r [1,D]
    const float* cl = (const float*)d_in[2];  // embed_candidates_l [N,D]
    const float* cr = (const float*)d_in[3];  // embed_candidates_r [N,D]
    const float* W  = (const float*)d_in[4];  // W_a [D,D]
    const float* ba = (const float*)d_in[5];  // b_a [1,D]
    float* out = (float*)d_out;
    float* ws  = (float*)d_ws;

    // ws layout (floats): alignp[2][KSPLIT][D] | alignv[2][D] | mP[2][B] | sP[2][B] | accP[2][B][D]
    const size_t fixed_f = (size_t)2 * KSPLIT * DDIM + (size_t)2 * DDIM;
    int B = 512;  // blocks per side; power of two so it divides NCAND
    while (B > 8) {
        size_t need = (fixed_f + (size_t)4 * B + (size_t)2 * B * DDIM) * sizeof(float);
        if (need <= ws_size) break;
        B >>= 1;
    }
    const int rpw = NCAND / (B * 4);  // rows per wave (4 waves per block)

    float* alignp = ws;
    float* alignv = alignp + (size_t)2 * KSPLIT * DDIM;
    float* mP     = alignv + (size_t)2 * DDIM;
    float* sP     = mP + (size_t)2 * B;
    float* accP   = sP + (size_t)2 * B;

    align_partial<<<dim3(DDIM / 1024, KSPLIT), 256, 0, stream>>>(wl, wr, W, alignp);
    align_finish<<<dim3(DDIM / 256), 256, 0, stream>>>(alignp, ba, alignv);
    score_accum<<<dim3(B, 2), 256, 0, stream>>>(cl, cr, alignv, accP, mP, sP, B, rpw);
    combine<<<dim3(DDIM / 256, 2), 256, 0, stream>>>(accP, mP, sP, out, B);
}

// Round 2
// 1029.315 us; speedup vs baseline: 1.1275x; 1.0430x over previous
//
#include <hip/hip_runtime.h>
#include <math.h>

#define DDIM 2048
#define NCAND 65536

typedef float f4 __attribute__((ext_vector_type(4)));

// ---------------------------------------------------------------------------
// Kernel A (fused): align[j] = tanh(sum_k word[k] * W[k,j] + b[j]), both sides.
// 128 WGs, each owns a 16-column slab of W (2048x16 = 128 KB, read once, NT).
// Thread t: jc = t&3 (which float4 of the 16 cols), kg = t>>2 (k-group of 32).
// Per wave-instr: 16 rows x 64 B contiguous segments -> full-line coalesced.
// LDS reduce over the 64 k-groups, then tanh + store. One dispatch replaces
// the old align_partial + align_finish pair (no alignp round-trip).
// ---------------------------------------------------------------------------
#define AWGS 128
#define AJC  16

__global__ __launch_bounds__(256) void align_fused(
    const float* __restrict__ wl, const float* __restrict__ wr,
    const float* __restrict__ W, const float* __restrict__ b,
    float* __restrict__ alignv)
{
    const int t  = threadIdx.x;
    const int jc = t & 3;        // 0..3 : float4 group within the 16-col slab
    const int kg = t >> 2;       // 0..63: k-group (32 consecutive k each)
    const int j0 = blockIdx.x * AJC;
    const int kbase = kg * 32;

    const float* Wp = W + (size_t)kbase * DDIM + j0 + jc * 4;
    f4 al = {0.f, 0.f, 0.f, 0.f};
    f4 ar = {0.f, 0.f, 0.f, 0.f};
#pragma unroll 8
    for (int i = 0; i < 32; ++i) {
        const f4 w4 = __builtin_nontemporal_load((const f4*)(Wp + (size_t)i * DDIM));
        const float cl = wl[kbase + i], cr = wr[kbase + i];
        al.x = fmaf(cl, w4.x, al.x); al.y = fmaf(cl, w4.y, al.y);
        al.z = fmaf(cl, w4.z, al.z); al.w = fmaf(cl, w4.w, al.w);
        ar.x = fmaf(cr, w4.x, ar.x); ar.y = fmaf(cr, w4.y, ar.y);
        ar.z = fmaf(cr, w4.z, ar.z); ar.w = fmaf(cr, w4.w, ar.w);
    }

    __shared__ float shA[64][AJC];
    __shared__ float shB[64][AJC];
    *(f4*)&shA[kg][jc * 4] = al;
    *(f4*)&shB[kg][jc * 4] = ar;
    __syncthreads();

    if (t < 2 * AJC) {                 // 32 threads finish: 2 sides x 16 cols
        const int side = t >> 4;
        const int c    = t & 15;
        const float (*sh)[AJC] = side ? shB : shA;
        float s0 = 0.f, s1 = 0.f, s2 = 0.f, s3 = 0.f;
        for (int g = 0; g < 64; g += 4) {
            s0 += sh[g][c]; s1 += sh[g + 1][c];
            s2 += sh[g + 2][c]; s3 += sh[g + 3][c];
        }
        const float s = ((s0 + s1) + (s2 + s3)) + b[j0 + c];
        alignv[(size_t)side * DDIM + j0 + c] = tanhf(s);
    }
}

// ---------------------------------------------------------------------------
// Kernel C: fused scores -> online softmax -> weighted accumulation.
// PER-WAVE: each wave owns rows_per_wave rows across all 2048 cols.
// This round: candidate loads are NON-TEMPORAL (each 64-B line is read by
// exactly one wave-instruction, once, chip-wide -> caching is pure overhead).
// Dot = 4 independent FMA chains; xor-butterfly (bit-identical across lanes);
// skip path for p - m < -25 (wgt < 1.4e-11 cannot alter fp32 state).
// ---------------------------------------------------------------------------
__global__ __launch_bounds__(256, 4) void score_accum(
    const float* __restrict__ cand_l, const float* __restrict__ cand_r,
    const float* __restrict__ alignv,
    float* __restrict__ accP, float* __restrict__ mP, float* __restrict__ sP,
    int B, int rows_per_wave)
{
    const int side = blockIdx.y;
    const float* __restrict__ cand  = (side == 0) ? cand_r : cand_l;
    const float* __restrict__ align = alignv + (size_t)side * DDIM;

    const int t = threadIdx.x;
    const int w = t >> 6;
    const int l = t & 63;
    const int cbase = l * 4;

    f4 al[8], acc[8];
#pragma unroll
    for (int c = 0; c < 8; ++c) {
        al[c]  = *(const f4*)(align + c * 256 + cbase);
        acc[c] = (f4){0.f, 0.f, 0.f, 0.f};
    }
    float m = -INFINITY, s = 0.f;

    const int row0 = (blockIdx.x * 4 + w) * rows_per_wave;
    for (int r = 0; r < rows_per_wave; ++r) {
        const float* rp = cand + (size_t)(row0 + r) * DDIM;
        f4 v[8];
#pragma unroll
        for (int c = 0; c < 8; ++c)
            v[c] = __builtin_nontemporal_load((const f4*)(rp + c * 256 + cbase));

        float pp[4] = {0.f, 0.f, 0.f, 0.f};
#pragma unroll
        for (int c = 0; c < 8; ++c) {
            float q = pp[c >> 1];
            q = fmaf(v[c].x, al[c].x, q);
            q = fmaf(v[c].y, al[c].y, q);
            q = fmaf(v[c].z, al[c].z, q);
            q = fmaf(v[c].w, al[c].w, q);
            pp[c >> 1] = q;
        }
        float p = (pp[0] + pp[1]) + (pp[2] + pp[3]);
#pragma unroll
        for (int off = 32; off > 0; off >>= 1)
            p += __shfl_xor(p, off, 64);
        // all lanes hold bit-identical p (xor-butterfly + commutative add)

        if (p > m) {                   // wave-uniform, ~ln(rows) times
            const float alpha = expf(m - p); // m=-inf first hit -> alpha=0
            m = p;
            s = fmaf(s, alpha, 1.f);   // new-max weight = 1
#pragma unroll
            for (int c = 0; c < 8; ++c) {
                acc[c].x = fmaf(acc[c].x, alpha, v[c].x);
                acc[c].y = fmaf(acc[c].y, alpha, v[c].y);
                acc[c].z = fmaf(acc[c].z, alpha, v[c].z);
                acc[c].w = fmaf(acc[c].w, alpha, v[c].w);
            }
        } else if (p - m >= -25.f) {   // contributes at fp32 resolution
            const float wgt = expf(p - m);
            s += wgt;
#pragma unroll
            for (int c = 0; c < 8; ++c) {
                acc[c].x = fmaf(wgt, v[c].x, acc[c].x);
                acc[c].y = fmaf(wgt, v[c].y, acc[c].y);
                acc[c].z = fmaf(wgt, v[c].z, acc[c].z);
                acc[c].w = fmaf(wgt, v[c].w, acc[c].w);
            }
        }
        // else: wgt < 1.4e-11 -> cannot alter s or acc in fp32; skip.
    }

    // ---- merge 4 wave-partials -> 1 block-partial via LDS (single barrier)
    __shared__ float sh_acc[4][DDIM];
    __shared__ float sh_m[4], sh_s[4];
#pragma unroll
    for (int c = 0; c < 8; ++c)
        *(f4*)(&sh_acc[w][c * 256 + cbase]) = acc[c];
    if (l == 0) { sh_m[w] = m; sh_s[w] = s; }
    __syncthreads();

    const float mB = fmaxf(fmaxf(sh_m[0], sh_m[1]), fmaxf(sh_m[2], sh_m[3]));
    const float e0 = expf(sh_m[0] - mB);
    const float e1 = expf(sh_m[1] - mB);
    const float e2 = expf(sh_m[2] - mB);
    const float e3 = expf(sh_m[3] - mB);
    const float sB = e0 * sh_s[0] + e1 * sh_s[1] + e2 * sh_s[2] + e3 * sh_s[3];

    float* accB = accP + (size_t)(side * B + blockIdx.x) * DDIM;
#pragma unroll
    for (int half = 0; half < 2; ++half) {
        const int col = half * 1024 + t * 4;
        const f4 a0 = *(const f4*)&sh_acc[0][col];
        const f4 a1 = *(const f4*)&sh_acc[1][col];
        const f4 a2 = *(const f4*)&sh_acc[2][col];
        const f4 a3 = *(const f4*)&sh_acc[3][col];
        f4 o;
        o.x = e0 * a0.x + e1 * a1.x + e2 * a2.x + e3 * a3.x;
        o.y = e0 * a0.y + e1 * a1.y + e2 * a2.y + e3 * a3.y;
        o.z = e0 * a0.z + e1 * a1.z + e2 * a2.z + e3 * a3.z;
        o.w = e0 * a0.w + e1 * a1.w + e2 * a2.w + e3 * a3.w;
        *(f4*)(accB + col) = o;
    }
    if (t == 0) {
        mP[side * B + blockIdx.x] = mB;
        sP[side * B + blockIdx.x] = sB;
    }
}

// ---------------------------------------------------------------------------
// Kernel D: combine block partials:
// out[j] = sum_b e^{m_b-M} acc_b[j] / sum_b e^{m_b-M} s_b
// Unrolled x4 with independent partials (breaks 512-deep serial chains).
// ---------------------------------------------------------------------------
__global__ void combine(const float* __restrict__ accP,
                        const float* __restrict__ mP,
                        const float* __restrict__ sP,
                        float* __restrict__ out, int B)
{
    const int side = blockIdx.y;
    const int j = blockIdx.x * blockDim.x + threadIdx.x;
    const float* m = mP + side * B;
    const float* s = sP + side * B;
    float M0 = -INFINITY, M1 = -INFINITY, M2 = -INFINITY, M3 = -INFINITY;
    for (int b = 0; b < B; b += 4) {
        M0 = fmaxf(M0, m[b]);
        M1 = fmaxf(M1, m[b + 1]);
        M2 = fmaxf(M2, m[b + 2]);
        M3 = fmaxf(M3, m[b + 3]);
    }
    const float M = fmaxf(fmaxf(M0, M1), fmaxf(M2, M3));

    float S0 = 0.f, S1 = 0.f, S2 = 0.f, S3 = 0.f;
    float n0 = 0.f, n1 = 0.f, n2 = 0.f, n3 = 0.f;
    const float* ap = accP + (size_t)side * B * DDIM + j;
    for (int b = 0; b < B; b += 4) {
        const float w0 = expf(m[b]     - M);
        const float w1 = expf(m[b + 1] - M);
        const float w2 = expf(m[b + 2] - M);
        const float w3 = expf(m[b + 3] - M);
        S0 += w0 * s[b];     S1 += w1 * s[b + 1];
        S2 += w2 * s[b + 2]; S3 += w3 * s[b + 3];
        n0 = fmaf(w0, ap[(size_t)(b)     * DDIM], n0);
        n1 = fmaf(w1, ap[(size_t)(b + 1) * DDIM], n1);
        n2 = fmaf(w2, ap[(size_t)(b + 2) * DDIM], n2);
        n3 = fmaf(w3, ap[(size_t)(b + 3) * DDIM], n3);
    }
    out[(size_t)side * DDIM + j] =
        ((n0 + n1) + (n2 + n3)) / ((S0 + S1) + (S2 + S3));
}

extern "C" void kernel_launch(void* const* d_in, const int* in_sizes, int n_in,
                              void* d_out, int out_size, void* d_ws, size_t ws_size,
                              hipStream_t stream) {
    const float* wl = (const float*)d_in[0];  // embed_word_l [1,D]
    const float* wr = (const float*)d_in[1];  // embed_word_r [1,D]
    const float* cl = (const float*)d_in[2];  // embed_candidates_l [N,D]
    const float* cr = (const float*)d_in[3];  // embed_candidates_r [N,D]
    const float* W  = (const float*)d_in[4];  // W_a [D,D]
    const float* ba = (const float*)d_in[5];  // b_a [1,D]
    float* out = (float*)d_out;
    float* ws  = (float*)d_ws;

    // ws layout (floats): alignv[2][D] | mP[2][B] | sP[2][B] | accP[2][B][D]
    const size_t fixed_f = (size_t)2 * DDIM;
    int B = 512;  // blocks per side; power of two so it divides NCAND
    while (B > 8) {
        size_t need = (fixed_f + (size_t)4 * B + (size_t)2 * B * DDIM) * sizeof(float);
        if (need <= ws_size) break;
        B >>= 1;
    }
    const int rpw = NCAND / (B * 4);  // rows per wave (4 waves per block)

    float* alignv = ws;
    float* mP     = alignv + (size_t)2 * DDIM;
    float* sP     = mP + (size_t)2 * B;
    float* accP   = sP + (size_t)2 * B;

    align_fused<<<dim3(AWGS), 256, 0, stream>>>(wl, wr, W, ba, alignv);
    score_accum<<<dim3(B, 2), 256, 0, stream>>>(cl, cr, alignv, accP, mP, sP, B, rpw);
    combine<<<dim3(DDIM / 256, 2), 256, 0, stream>>>(accP, mP, sP, out, B);
}